// Round 7
// baseline (400.312 us; speedup 1.0000x reference)
//
#include <hip/hip_runtime.h>
#include <cstdint>
#include <cstddef>

typedef unsigned short u16;
typedef __attribute__((ext_vector_type(4))) float f32x4;
typedef __attribute__((ext_vector_type(8))) short short8;
typedef __attribute__((ext_vector_type(4))) unsigned short u16x4;
typedef short8 __attribute__((may_alias)) short8_a;
typedef uint2 __attribute__((may_alias)) uint2_a;

#define NH 16
#define ED 1024
#define HD 64
#define SEQ 4096
#define SKV 1024

// 0.125 (1/sqrt(64)) * log2(e), folded into Q at projection time
#define QSCALE 0.1803368801111204f

__device__ __forceinline__ u16 f2bf(float f) {
  unsigned u = __builtin_bit_cast(unsigned, f);
  u += 0x7fffu + ((u >> 16) & 1u);
  return (u16)(u >> 16);
}

__device__ __forceinline__ float fexp2(float x) {
  float r;
  asm("v_exp_f32 %0, %1" : "=v"(r) : "v"(x));
  return r;
}

__device__ __forceinline__ unsigned cvtpk(float lo, float hi) {
  unsigned r;
  asm("v_cvt_pk_bf16_f32 %0, %1, %2" : "=v"(r) : "v"(lo), "v"(hi));
  return r;
}

__device__ __forceinline__ void gload16(const void* g, void* l) {
  __builtin_amdgcn_global_load_lds((const __attribute__((address_space(1))) void*)g,
                                   (__attribute__((address_space(3))) void*)l, 16, 0, 0);
}

__device__ __forceinline__ f32x4 mfma16(short8 a, short8 b, f32x4 c) {
  return __builtin_amdgcn_mfma_f32_16x16x32_bf16(a, b, c, 0, 0, 0);
}

// ---------------- prep: x fp32->bf16 + 4x weight transpose+convert ----------------
__global__ __launch_bounds__(256) void prep_kernel(
    const float* __restrict__ x, u16* __restrict__ x16,
    const float* __restrict__ Wq, const float* __restrict__ Wk,
    const float* __restrict__ Wv, const float* __restrict__ Wo,
    u16* __restrict__ Wqt, u16* __restrict__ Wkt,
    u16* __restrict__ Wvt, u16* __restrict__ Wot) {
  __shared__ float t[64][65];
  int bx = blockIdx.x;
  if (bx < 8192) {
    int i = bx * 256 + threadIdx.x;
    f32x4 v = ((const f32x4*)x)[i];
    u16x4 o;
#pragma unroll
    for (int j = 0; j < 4; ++j) o[j] = f2bf(v[j]);
    ((u16x4*)x16)[i] = o;
    return;
  }
  int tt = bx - 8192;
  int wi = tt >> 8;
  tt &= 255;
  const float* W = (wi == 0) ? Wq : (wi == 1) ? Wk : (wi == 2) ? Wv : Wo;
  u16* Wt = (wi == 0) ? Wqt : (wi == 1) ? Wkt : (wi == 2) ? Wvt : Wot;
  int kb = (tt >> 4) * 64, nb = (tt & 15) * 64;
  int tx = threadIdx.x & 15, ty = threadIdx.x >> 4;
#pragma unroll
  for (int j = 0; j < 4; ++j) {
    int row = ty + j * 16;
    f32x4 v = *(const f32x4*)&W[(size_t)(kb + row) * ED + nb + tx * 4];
#pragma unroll
    for (int i = 0; i < 4; ++i) t[row][tx * 4 + i] = v[i];
  }
  __syncthreads();
#pragma unroll
  for (int j = 0; j < 4; ++j) {
    int n = ty + j * 16;
    u16x4 o;
#pragma unroll
    for (int i = 0; i < 4; ++i) o[i] = f2bf(t[tx * 4 + i][n]);
    *(u16x4*)&Wt[(size_t)(nb + n) * ED + kb + tx * 4] = o;
  }
}

// ---------------- merged QKV GEMM (XCD-chunked block swizzle) ----------------
// logical grid (8, 96): y<64 -> Q (pre-scaled by QSCALE); y in [64,80) -> K;
// y in [80,96) -> V transposed.
__global__ __launch_bounds__(256) void qkv_gemm(
    const u16* __restrict__ A,
    const u16* __restrict__ Wqt, const u16* __restrict__ Wkt, const u16* __restrict__ Wvt,
    const float* __restrict__ bq, const float* __restrict__ bk, const float* __restrict__ bv,
    u16* __restrict__ Q16, u16* __restrict__ K16, u16* __restrict__ VT16) {
  __shared__ u16 Al[128 * 32];
  __shared__ u16 Bl[128 * 32];
  const int tid = threadIdx.x;
  const int w = tid >> 6, lane = tid & 63;
  // XCD swizzle: hw id (x-fastest) -> chunked y per XCD (768 % 8 == 0, bijective)
  int flat = blockIdx.x + 8 * blockIdx.y;
  int nf = (flat & 7) * 96 + (flat >> 3);
  const int bxs = nf & 7, by = nf >> 3;
  int which, mblk;
  if (by < 64) { which = 0; mblk = by; }
  else if (by < 80) { which = 1; mblk = by - 64; }
  else { which = 2; mblk = by - 80; }
  const int rowmult = (which == 0) ? 1 : 4;
  const u16* Bt = (which == 0) ? Wqt : (which == 1) ? Wkt : Wvt;
  const float* bias = (which == 0) ? bq : (which == 1) ? bk : bv;
  const int m0 = mblk * 128, n0 = bxs * 128;
  const int wr = w >> 1, wc = w & 1;
  f32x4 acc[4][4];
#pragma unroll
  for (int i = 0; i < 4; ++i)
#pragma unroll
    for (int j = 0; j < 4; ++j) acc[i][j] = (f32x4){0.f, 0.f, 0.f, 0.f};

  const int srow = w * 16 + (lane >> 2);
  const int scol = (lane & 3) * 8;
  const u16* Ag0 = A + (size_t)(m0 + srow) * rowmult * ED + scol;
  const u16* Ag1 = A + (size_t)(m0 + srow + 64) * rowmult * ED + scol;
  const u16* Bg0 = Bt + (size_t)(n0 + srow) * ED + scol;
  const u16* Bg1 = Bt + (size_t)(n0 + srow + 64) * ED + scol;
  u16* Al0 = &Al[(w * 16) * 32];
  u16* Al1 = &Al[(64 + w * 16) * 32];
  u16* Bl0 = &Bl[(w * 16) * 32];
  u16* Bl1 = &Bl[(64 + w * 16) * 32];

  for (int k0 = 0; k0 < ED; k0 += 32) {
    gload16(Ag0 + k0, Al0);
    gload16(Ag1 + k0, Al1);
    gload16(Bg0 + k0, Bl0);
    gload16(Bg1 + k0, Bl1);
    __syncthreads();
    short8 af[4], bfr[4];
#pragma unroll
    for (int i = 0; i < 4; ++i)
      af[i] = *(const short8*)&Al[(wr * 64 + i * 16 + (lane & 15)) * 32 + (lane >> 4) * 8];
#pragma unroll
    for (int i = 0; i < 4; ++i)
      bfr[i] = *(const short8*)&Bl[(wc * 64 + i * 16 + (lane & 15)) * 32 + (lane >> 4) * 8];
#pragma unroll
    for (int i = 0; i < 4; ++i)
#pragma unroll
      for (int j = 0; j < 4; ++j)
        acc[i][j] = mfma16(af[i], bfr[j], acc[i][j]);
    __syncthreads();
  }

  const int r0 = m0 + wr * 64, c0g = n0 + wc * 64;
  if (which == 0 || which == 1) {
    u16* o = (which == 0) ? Q16 : K16;
    const int sxlog2 = (which == 0) ? 12 : 10;
    const int Sx = 1 << sxlog2;
    const float scl = (which == 0) ? QSCALE : 1.0f;
#pragma unroll
    for (int i = 0; i < 4; ++i) {
#pragma unroll
      for (int j = 0; j < 4; ++j) {
        int Cc = c0g + j * 16 + (lane & 15);
        int h = Cc >> 6, d = Cc & 63;
        float bv2 = bias[Cc];
#pragma unroll
        for (int r = 0; r < 4; ++r) {
          int R = r0 + i * 16 + (lane >> 4) * 4 + r;
          int b = R >> sxlog2, s = R & (Sx - 1);
          o[(((size_t)b * NH + h) * Sx + s) * HD + d] = f2bf((acc[i][j][r] + bv2) * scl);
        }
      }
    }
  } else {
    u16* o = VT16;
#pragma unroll
    for (int i = 0; i < 4; ++i) {
#pragma unroll
      for (int j = 0; j < 4; ++j) {
        int Cc = c0g + j * 16 + (lane & 15);
        int h = Cc >> 6, d = Cc & 63;
        float bv2 = bias[Cc];
#pragma unroll
        for (int r = 0; r < 4; ++r) {
          int R = r0 + i * 16 + (lane >> 4) * 4 + r;
          int b = R >> 10, s = R & 1023;
          o[(((size_t)b * NH + h) * HD + d) * SKV + s] = f2bf(acc[i][j][r] + bv2);
        }
      }
    }
  }
}

// ---------------- O projection: out = ctx @ Wot^T + bo, fp32 out ----------------
__global__ __launch_bounds__(256) void out_gemm(const u16* __restrict__ A,
                                                const u16* __restrict__ Bt,
                                                const float* __restrict__ bias,
                                                float* __restrict__ o) {
  __shared__ u16 Al[128 * 32];
  __shared__ u16 Bl[128 * 32];
  const int tid = threadIdx.x;
  const int w = tid >> 6, lane = tid & 63;
  // XCD swizzle (512 % 8 == 0, bijective)
  int flat = blockIdx.x + 8 * blockIdx.y;
  int nf = (flat & 7) * 64 + (flat >> 3);
  const int m0 = (nf >> 3) * 128, n0 = (nf & 7) * 128;
  const int wr = w >> 1, wc = w & 1;
  f32x4 acc[4][4];
#pragma unroll
  for (int i = 0; i < 4; ++i)
#pragma unroll
    for (int j = 0; j < 4; ++j) acc[i][j] = (f32x4){0.f, 0.f, 0.f, 0.f};

  const int srow = w * 16 + (lane >> 2);
  const int scol = (lane & 3) * 8;
  const u16* Ag0 = A + (size_t)(m0 + srow) * ED + scol;
  const u16* Ag1 = A + (size_t)(m0 + srow + 64) * ED + scol;
  const u16* Bg0 = Bt + (size_t)(n0 + srow) * ED + scol;
  const u16* Bg1 = Bt + (size_t)(n0 + srow + 64) * ED + scol;
  u16* Al0 = &Al[(w * 16) * 32];
  u16* Al1 = &Al[(64 + w * 16) * 32];
  u16* Bl0 = &Bl[(w * 16) * 32];
  u16* Bl1 = &Bl[(64 + w * 16) * 32];

  for (int k0 = 0; k0 < ED; k0 += 32) {
    gload16(Ag0 + k0, Al0);
    gload16(Ag1 + k0, Al1);
    gload16(Bg0 + k0, Bl0);
    gload16(Bg1 + k0, Bl1);
    __syncthreads();
    short8 af[4], bfr[4];
#pragma unroll
    for (int i = 0; i < 4; ++i)
      af[i] = *(const short8*)&Al[(wr * 64 + i * 16 + (lane & 15)) * 32 + (lane >> 4) * 8];
#pragma unroll
    for (int i = 0; i < 4; ++i)
      bfr[i] = *(const short8*)&Bl[(wc * 64 + i * 16 + (lane & 15)) * 32 + (lane >> 4) * 8];
#pragma unroll
    for (int i = 0; i < 4; ++i)
#pragma unroll
      for (int j = 0; j < 4; ++j)
        acc[i][j] = mfma16(af[i], bfr[j], acc[i][j]);
    __syncthreads();
  }

  const int r0 = m0 + wr * 64, c0g = n0 + wc * 64;
#pragma unroll
  for (int i = 0; i < 4; ++i) {
#pragma unroll
    for (int j = 0; j < 4; ++j) {
      int Cc = c0g + j * 16 + (lane & 15);
      float bv2 = bias[Cc];
#pragma unroll
      for (int r = 0; r < 4; ++r) {
        int R = r0 + i * 16 + (lane >> 4) * 4 + r;
        o[(size_t)R * ED + Cc] = acc[i][j][r] + bv2;
      }
    }
  }
}

// ---------------- flash attention: NO K/V staging (L2-resident), no barriers ----------------
// K/VT per (b,h) = 256 KB, shared by 64 blocks -> read fragments directly from
// global (L2 hit). P stays wave-private LDS (8 KB total) -> occupancy 8 blocks/CU.
// XCD-chunked: each XCD owns 4 consecutive bh (1 MB < 4 MB L2).
__global__ __launch_bounds__(256) void attn_kernel(const u16* __restrict__ Q,
                                                   const u16* __restrict__ K,
                                                   const u16* __restrict__ VT,
                                                   u16* __restrict__ ctx) {
  __shared__ u16 Pl[4 * 16 * 64];   // per-wave P [q][k] swizzled
  const int tid = threadIdx.x, w = tid >> 6, lane = tid & 63;
  // bijective XCD chunking: 2048 blocks, 8 XCDs -> 256 each; bh-major within XCD
  int flat = blockIdx.x;
  int nf = (flat & 7) * 256 + (flat >> 3);
  const int bh = nf >> 6, qt = nf & 63;
  const int b = bh >> 4, h = bh & 15;

  const u16* Qp = Q + ((size_t)bh * SEQ + qt * 64 + w * 16) * HD;
  const int g4 = lane >> 4;           // lane group 0..3
  const int sw7 = lane & 7;
  const int q = lane & 15;

  short8 qf0 = *(const short8_a*)&Qp[(lane & 15) * HD + g4 * 8];
  short8 qf1 = *(const short8_a*)&Qp[(lane & 15) * HD + g4 * 8 + 32];
  const u16* Kb = K + (size_t)bh * SKV * HD;
  const u16* VTb = VT + (size_t)bh * HD * SKV;

  float lp = 0.f;
  f32x4 cacc[4];
#pragma unroll
  for (int i = 0; i < 4; ++i) cacc[i] = (f32x4){0.f, 0.f, 0.f, 0.f};

  // P write element-offsets (constant across tiles)
  int poff[4];
#pragma unroll
  for (int fk = 0; fk < 4; ++fk) {
    int gr = 2 * fk + (g4 >> 1);
    poff[fk] = q * 64 + ((gr ^ sw7) * 8) + 4 * (g4 & 1);
  }

  u16* Pw = &Pl[w * 1024];
  // per-lane fragment base addresses
  const u16* Kfrag = Kb + (size_t)(lane & 15) * HD + g4 * 8;      // + k*HD + {0,32}
  const u16* Vfrag = VTb + (size_t)(lane & 15) * SKV + g4 * 8;    // + d16*SKV + kt*64 + {0,32}

  for (int kt = 0; kt < 16; ++kt) {
    // QK^T swapped: S[k rows][q cols]; A=K fragment from GLOBAL (L2), B=Q regs
    f32x4 sv[4];
    __builtin_amdgcn_s_setprio(1);
#pragma unroll
    for (int fk = 0; fk < 4; ++fk) {
      const u16* kr = Kfrag + (size_t)(kt * 64 + fk * 16) * HD;
      short8 a0 = *(const short8_a*)kr;
      short8 a1 = *(const short8_a*)(kr + 32);
      f32x4 z = (f32x4){0.f, 0.f, 0.f, 0.f};
      z = mfma16(a0, qf0, z);
      z = mfma16(a1, qf1, z);
      sv[fk] = z;
    }
    __builtin_amdgcn_s_setprio(0);

    // P = exp2(S); pack pairs -> ds_write_b64 into wave-private LDS
#pragma unroll
    for (int fk = 0; fk < 4; ++fk) {
      float p0 = fexp2(sv[fk][0]);
      float p1 = fexp2(sv[fk][1]);
      float p2 = fexp2(sv[fk][2]);
      float p3 = fexp2(sv[fk][3]);
      lp += (p0 + p1) + (p2 + p3);
      uint2 pk;
      pk.x = cvtpk(p0, p1);
      pk.y = cvtpk(p2, p3);
      *(uint2_a*)&Pw[poff[fk]] = pk;
    }

    // PV: ctx[16q x 64d] += P[16q x 64k] @ V; V fragment from GLOBAL (L2)
    short8 pa0 = *(const short8_a*)&Pw[(lane & 15) * 64 + ((g4 ^ sw7) * 8)];
    short8 pa1 = *(const short8_a*)&Pw[(lane & 15) * 64 + (((g4 + 4) ^ sw7) * 8)];
    __builtin_amdgcn_s_setprio(1);
#pragma unroll
    for (int fd = 0; fd < 4; ++fd) {
      const u16* vr = Vfrag + (size_t)(fd * 16) * SKV + kt * 64;
      short8 vb0 = *(const short8_a*)vr;
      short8 vb1 = *(const short8_a*)(vr + 32);
      cacc[fd] = mfma16(pa0, vb0, cacc[fd]);
      cacc[fd] = mfma16(pa1, vb1, cacc[fd]);
    }
    __builtin_amdgcn_s_setprio(0);
  }

  // l reduction: lane holds partial for q=lane&15; sum across the 4 groups
  lp += __shfl_xor(lp, 16);
  lp += __shfl_xor(lp, 32);

  // epilogue: ctx bf16 in [B,S,E]; row q0+r needs l of q=(lane>>4)*4+r
  const int q0 = qt * 64 + w * 16 + (lane >> 4) * 4;
#pragma unroll
  for (int r = 0; r < 4; ++r) {
    float inv = 1.f / __shfl(lp, (lane >> 4) * 4 + r);
#pragma unroll
    for (int fd = 0; fd < 4; ++fd) {
      int d = fd * 16 + (lane & 15);
      ctx[((size_t)b * SEQ + q0 + r) * ED + h * HD + d] = f2bf(cacc[fd][r] * inv);
    }
  }
}

extern "C" void kernel_launch(void* const* d_in, const int* in_sizes, int n_in,
                              void* d_out, int out_size, void* d_ws, size_t ws_size,
                              hipStream_t stream) {
  (void)in_sizes; (void)n_in; (void)out_size; (void)ws_size;
  const float* x  = (const float*)d_in[0];
  const float* Wq = (const float*)d_in[1];
  const float* bq = (const float*)d_in[2];
  const float* Wk = (const float*)d_in[3];
  const float* bk = (const float*)d_in[4];
  const float* Wv = (const float*)d_in[5];
  const float* bv = (const float*)d_in[6];
  const float* Wo = (const float*)d_in[7];
  const float* bo = (const float*)d_in[8];

  char* ws = (char*)d_ws;
  u16* x16 = (u16*)(ws);                       // 16 MB (reused as ctx16)
  u16* Wqt = (u16*)(ws + (16ull << 20));       // 2 MB
  u16* Wkt = (u16*)(ws + (18ull << 20));       // 2 MB
  u16* Wvt = (u16*)(ws + (20ull << 20));       // 2 MB
  u16* Wot = (u16*)(ws + (22ull << 20));       // 2 MB
  u16* Q16 = (u16*)(ws + (24ull << 20));       // 16 MB
  u16* K16 = (u16*)(ws + (40ull << 20));       // 4 MB
  u16* VT16 = (u16*)(ws + (44ull << 20));      // 4 MB  -> total 48 MB
  u16* ctx16 = x16;

  prep_kernel<<<9216, 256, 0, stream>>>(x, x16, Wq, Wk, Wv, Wo, Wqt, Wkt, Wvt, Wot);

  qkv_gemm<<<dim3(8, 96), 256, 0, stream>>>(x16, Wqt, Wkt, Wvt, bq, bk, bv,
                                            Q16, K16, VT16);

  attn_kernel<<<2048, 256, 0, stream>>>(Q16, K16, VT16, ctx16);

  out_gemm<<<dim3(8, 64), 256, 0, stream>>>(ctx16, Wot, bo, (float*)d_out);
}

// Round 8
// 229.296 us; speedup vs baseline: 1.7458x; 1.7458x over previous
//
#include <hip/hip_runtime.h>
#include <cstdint>
#include <cstddef>

typedef unsigned short u16;
typedef __attribute__((ext_vector_type(4))) float f32x4;
typedef __attribute__((ext_vector_type(8))) short short8;
typedef __attribute__((ext_vector_type(4))) unsigned short u16x4;
typedef short8 __attribute__((may_alias)) short8_a;
typedef uint2 __attribute__((may_alias)) uint2_a;

#define NH 16
#define ED 1024
#define HD 64
#define SEQ 4096
#define SKV 1024

// 0.125 (1/sqrt(64)) * log2(e), folded into Q at projection time
#define QSCALE 0.1803368801111204f

__device__ __forceinline__ u16 f2bf(float f) {
  unsigned u = __builtin_bit_cast(unsigned, f);
  u += 0x7fffu + ((u >> 16) & 1u);
  return (u16)(u >> 16);
}

__device__ __forceinline__ float fexp2(float x) {
  float r;
  asm("v_exp_f32 %0, %1" : "=v"(r) : "v"(x));
  return r;
}

__device__ __forceinline__ unsigned cvtpk(float lo, float hi) {
  unsigned r;
  asm("v_cvt_pk_bf16_f32 %0, %1, %2" : "=v"(r) : "v"(lo), "v"(hi));
  return r;
}

__device__ __forceinline__ void gload16(const void* g, void* l) {
  __builtin_amdgcn_global_load_lds((const __attribute__((address_space(1))) void*)g,
                                   (__attribute__((address_space(3))) void*)l, 16, 0, 0);
}

__device__ __forceinline__ f32x4 mfma16(short8 a, short8 b, f32x4 c) {
  return __builtin_amdgcn_mfma_f32_16x16x32_bf16(a, b, c, 0, 0, 0);
}

// ---------------- prep: x fp32->bf16 + 4x weight transpose+convert ----------------
__global__ __launch_bounds__(256) void prep_kernel(
    const float* __restrict__ x, u16* __restrict__ x16,
    const float* __restrict__ Wq, const float* __restrict__ Wk,
    const float* __restrict__ Wv, const float* __restrict__ Wo,
    u16* __restrict__ Wqt, u16* __restrict__ Wkt,
    u16* __restrict__ Wvt, u16* __restrict__ Wot) {
  __shared__ float t[64][65];
  int bx = blockIdx.x;
  if (bx < 8192) {
    int i = bx * 256 + threadIdx.x;
    f32x4 v = ((const f32x4*)x)[i];
    u16x4 o;
#pragma unroll
    for (int j = 0; j < 4; ++j) o[j] = f2bf(v[j]);
    ((u16x4*)x16)[i] = o;
    return;
  }
  int tt = bx - 8192;
  int wi = tt >> 8;
  tt &= 255;
  const float* W = (wi == 0) ? Wq : (wi == 1) ? Wk : (wi == 2) ? Wv : Wo;
  u16* Wt = (wi == 0) ? Wqt : (wi == 1) ? Wkt : (wi == 2) ? Wvt : Wot;
  int kb = (tt >> 4) * 64, nb = (tt & 15) * 64;
  int tx = threadIdx.x & 15, ty = threadIdx.x >> 4;
#pragma unroll
  for (int j = 0; j < 4; ++j) {
    int row = ty + j * 16;
    f32x4 v = *(const f32x4*)&W[(size_t)(kb + row) * ED + nb + tx * 4];
#pragma unroll
    for (int i = 0; i < 4; ++i) t[row][tx * 4 + i] = v[i];
  }
  __syncthreads();
#pragma unroll
  for (int j = 0; j < 4; ++j) {
    int n = ty + j * 16;
    u16x4 o;
#pragma unroll
    for (int i = 0; i < 4; ++i) o[i] = f2bf(t[tx * 4 + i][n]);
    *(u16x4*)&Wt[(size_t)(nb + n) * ED + kb + tx * 4] = o;
  }
}

// ---------------- merged QKV GEMM (XCD-chunked block swizzle) ----------------
__global__ __launch_bounds__(256) void qkv_gemm(
    const u16* __restrict__ A,
    const u16* __restrict__ Wqt, const u16* __restrict__ Wkt, const u16* __restrict__ Wvt,
    const float* __restrict__ bq, const float* __restrict__ bk, const float* __restrict__ bv,
    u16* __restrict__ Q16, u16* __restrict__ K16, u16* __restrict__ VT16) {
  __shared__ u16 Al[128 * 32];
  __shared__ u16 Bl[128 * 32];
  const int tid = threadIdx.x;
  const int w = tid >> 6, lane = tid & 63;
  int flat = blockIdx.x + 8 * blockIdx.y;
  int nf = (flat & 7) * 96 + (flat >> 3);
  const int bxs = nf & 7, by = nf >> 3;
  int which, mblk;
  if (by < 64) { which = 0; mblk = by; }
  else if (by < 80) { which = 1; mblk = by - 64; }
  else { which = 2; mblk = by - 80; }
  const int rowmult = (which == 0) ? 1 : 4;
  const u16* Bt = (which == 0) ? Wqt : (which == 1) ? Wkt : Wvt;
  const float* bias = (which == 0) ? bq : (which == 1) ? bk : bv;
  const int m0 = mblk * 128, n0 = bxs * 128;
  const int wr = w >> 1, wc = w & 1;
  f32x4 acc[4][4];
#pragma unroll
  for (int i = 0; i < 4; ++i)
#pragma unroll
    for (int j = 0; j < 4; ++j) acc[i][j] = (f32x4){0.f, 0.f, 0.f, 0.f};

  const int srow = w * 16 + (lane >> 2);
  const int scol = (lane & 3) * 8;
  const u16* Ag0 = A + (size_t)(m0 + srow) * rowmult * ED + scol;
  const u16* Ag1 = A + (size_t)(m0 + srow + 64) * rowmult * ED + scol;
  const u16* Bg0 = Bt + (size_t)(n0 + srow) * ED + scol;
  const u16* Bg1 = Bt + (size_t)(n0 + srow + 64) * ED + scol;
  u16* Al0 = &Al[(w * 16) * 32];
  u16* Al1 = &Al[(64 + w * 16) * 32];
  u16* Bl0 = &Bl[(w * 16) * 32];
  u16* Bl1 = &Bl[(64 + w * 16) * 32];

  for (int k0 = 0; k0 < ED; k0 += 32) {
    gload16(Ag0 + k0, Al0);
    gload16(Ag1 + k0, Al1);
    gload16(Bg0 + k0, Bl0);
    gload16(Bg1 + k0, Bl1);
    __syncthreads();
    short8 af[4], bfr[4];
#pragma unroll
    for (int i = 0; i < 4; ++i)
      af[i] = *(const short8*)&Al[(wr * 64 + i * 16 + (lane & 15)) * 32 + (lane >> 4) * 8];
#pragma unroll
    for (int i = 0; i < 4; ++i)
      bfr[i] = *(const short8*)&Bl[(wc * 64 + i * 16 + (lane & 15)) * 32 + (lane >> 4) * 8];
#pragma unroll
    for (int i = 0; i < 4; ++i)
#pragma unroll
      for (int j = 0; j < 4; ++j)
        acc[i][j] = mfma16(af[i], bfr[j], acc[i][j]);
    __syncthreads();
  }

  const int r0 = m0 + wr * 64, c0g = n0 + wc * 64;
  if (which == 0 || which == 1) {
    u16* o = (which == 0) ? Q16 : K16;
    const int sxlog2 = (which == 0) ? 12 : 10;
    const int Sx = 1 << sxlog2;
    const float scl = (which == 0) ? QSCALE : 1.0f;
#pragma unroll
    for (int i = 0; i < 4; ++i) {
#pragma unroll
      for (int j = 0; j < 4; ++j) {
        int Cc = c0g + j * 16 + (lane & 15);
        int h = Cc >> 6, d = Cc & 63;
        float bv2 = bias[Cc];
#pragma unroll
        for (int r = 0; r < 4; ++r) {
          int R = r0 + i * 16 + (lane >> 4) * 4 + r;
          int b = R >> sxlog2, s = R & (Sx - 1);
          o[(((size_t)b * NH + h) * Sx + s) * HD + d] = f2bf((acc[i][j][r] + bv2) * scl);
        }
      }
    }
  } else {
    u16* o = VT16;
#pragma unroll
    for (int i = 0; i < 4; ++i) {
#pragma unroll
      for (int j = 0; j < 4; ++j) {
        int Cc = c0g + j * 16 + (lane & 15);
        int h = Cc >> 6, d = Cc & 63;
        float bv2 = bias[Cc];
#pragma unroll
        for (int r = 0; r < 4; ++r) {
          int R = r0 + i * 16 + (lane >> 4) * 4 + r;
          int b = R >> 10, s = R & 1023;
          o[(((size_t)b * NH + h) * HD + d) * SKV + s] = f2bf(acc[i][j][r] + bv2);
        }
      }
    }
  }
}

// ---------------- O projection: out = ctx @ Wot^T + bo, fp32 out ----------------
__global__ __launch_bounds__(256) void out_gemm(const u16* __restrict__ A,
                                                const u16* __restrict__ Bt,
                                                const float* __restrict__ bias,
                                                float* __restrict__ o) {
  __shared__ u16 Al[128 * 32];
  __shared__ u16 Bl[128 * 32];
  const int tid = threadIdx.x;
  const int w = tid >> 6, lane = tid & 63;
  int flat = blockIdx.x + 8 * blockIdx.y;
  int nf = (flat & 7) * 64 + (flat >> 3);
  const int m0 = (nf >> 3) * 128, n0 = (nf & 7) * 128;
  const int wr = w >> 1, wc = w & 1;
  f32x4 acc[4][4];
#pragma unroll
  for (int i = 0; i < 4; ++i)
#pragma unroll
    for (int j = 0; j < 4; ++j) acc[i][j] = (f32x4){0.f, 0.f, 0.f, 0.f};

  const int srow = w * 16 + (lane >> 2);
  const int scol = (lane & 3) * 8;
  const u16* Ag0 = A + (size_t)(m0 + srow) * ED + scol;
  const u16* Ag1 = A + (size_t)(m0 + srow + 64) * ED + scol;
  const u16* Bg0 = Bt + (size_t)(n0 + srow) * ED + scol;
  const u16* Bg1 = Bt + (size_t)(n0 + srow + 64) * ED + scol;
  u16* Al0 = &Al[(w * 16) * 32];
  u16* Al1 = &Al[(64 + w * 16) * 32];
  u16* Bl0 = &Bl[(w * 16) * 32];
  u16* Bl1 = &Bl[(64 + w * 16) * 32];

  for (int k0 = 0; k0 < ED; k0 += 32) {
    gload16(Ag0 + k0, Al0);
    gload16(Ag1 + k0, Al1);
    gload16(Bg0 + k0, Bl0);
    gload16(Bg1 + k0, Bl1);
    __syncthreads();
    short8 af[4], bfr[4];
#pragma unroll
    for (int i = 0; i < 4; ++i)
      af[i] = *(const short8*)&Al[(wr * 64 + i * 16 + (lane & 15)) * 32 + (lane >> 4) * 8];
#pragma unroll
    for (int i = 0; i < 4; ++i)
      bfr[i] = *(const short8*)&Bl[(wc * 64 + i * 16 + (lane & 15)) * 32 + (lane >> 4) * 8];
#pragma unroll
    for (int i = 0; i < 4; ++i)
#pragma unroll
      for (int j = 0; j < 4; ++j)
        acc[i][j] = mfma16(af[i], bfr[j], acc[i][j]);
    __syncthreads();
  }

  const int r0 = m0 + wr * 64, c0g = n0 + wc * 64;
#pragma unroll
  for (int i = 0; i < 4; ++i) {
#pragma unroll
    for (int j = 0; j < 4; ++j) {
      int Cc = c0g + j * 16 + (lane & 15);
      float bv2 = bias[Cc];
#pragma unroll
      for (int r = 0; r < 4; ++r) {
        int R = r0 + i * 16 + (lane >> 4) * 4 + r;
        o[(size_t)R * ED + Cc] = acc[i][j][r] + bv2;
      }
    }
  }
}

// ---------------- flash attention: LDS-staged dbuf K/V, 32 q-rows per wave ----------------
// Round-6 structure (proven 62.6us) + 2x q-rows/wave: block covers 128 q-rows,
// grid 1024 = exactly 4 blocks/CU. Staging+barriers per q-row halve; K-frag LDS
// reads amortize over both q-groups. P single wave-private buffer, reused per group.
__global__ __launch_bounds__(256) void attn_kernel(const u16* __restrict__ Q,
                                                   const u16* __restrict__ K,
                                                   const u16* __restrict__ VT,
                                                   u16* __restrict__ ctx) {
  __shared__ u16 Kl[2][64 * 64];    // [k][d] swizzled, double-buffered
  __shared__ u16 Vl[2][64 * 64];    // [d][k] swizzled, double-buffered
  __shared__ u16 Pl[4 * 16 * 64];   // per-wave P [q][k] swizzled (reused per q-group)
  const int tid = threadIdx.x, w = tid >> 6, lane = tid & 63;
  // bijective XCD chunking: 1024 blocks, 8 XCDs -> 128 each; bh-major within XCD
  int flat = blockIdx.x;
  int nf = (flat & 7) * 128 + (flat >> 3);
  const int bh = nf >> 5, qt = nf & 31;   // qt: 128-row tile index
  const int b = bh >> 4, h = bh & 15;

  const int g4 = lane >> 4;           // lane group 0..3
  const int sw7 = lane & 7;
  const int q = lane & 15;

  const u16* Qp = Q + ((size_t)bh * SEQ + qt * 128 + w * 32) * HD;
  short8 qf[2][2];
#pragma unroll
  for (int u = 0; u < 2; ++u) {
    qf[u][0] = *(const short8_a*)&Qp[(u * 16 + q) * HD + g4 * 8];
    qf[u][1] = *(const short8_a*)&Qp[(u * 16 + q) * HD + g4 * 8 + 32];
  }
  const u16* Kb = K + (size_t)bh * SKV * HD;
  const u16* VTb = VT + (size_t)bh * HD * SKV;

  float lp[2] = {0.f, 0.f};
  f32x4 cacc[2][4];
#pragma unroll
  for (int u = 0; u < 2; ++u)
#pragma unroll
    for (int i = 0; i < 4; ++i) cacc[u][i] = (f32x4){0.f, 0.f, 0.f, 0.f};

  const int srow = lane >> 3;
  const int scolswz = ((lane & 7) ^ (lane >> 3)) * 8;

  // P write element-offsets (constant across tiles)
  int poff[4];
#pragma unroll
  for (int fk = 0; fk < 4; ++fk) {
    int gr = 2 * fk + (g4 >> 1);
    poff[fk] = q * 64 + ((gr ^ sw7) * 8) + 4 * (g4 & 1);
  }

  // running staging pointers (advance by constant stride; no per-tile addr math)
  const u16* gK0 = Kb + (size_t)(w * 8 + srow) * HD + scolswz;
  const u16* gK1 = Kb + (size_t)(32 + w * 8 + srow) * HD + scolswz;
  const u16* gV0 = VTb + (size_t)(w * 8 + srow) * SKV + scolswz;
  const u16* gV1 = VTb + (size_t)(32 + w * 8 + srow) * SKV + scolswz;

  auto stage = [&](int buf) {
    gload16(gK0, &Kl[buf][(w * 8) * 64]);
    gload16(gK1, &Kl[buf][(32 + w * 8) * 64]);
    gload16(gV0, &Vl[buf][(w * 8) * 64]);
    gload16(gV1, &Vl[buf][(32 + w * 8) * 64]);
    gK0 += 64 * HD; gK1 += 64 * HD; gV0 += 64; gV1 += 64;
  };

  stage(0);
  u16* Pw = &Pl[w * 1024];

  for (int kt = 0; kt < 16; ++kt) {
    const int cur = kt & 1;
    __syncthreads();                 // drains this wave's stage of buf `cur`
    if (kt < 15) stage(cur ^ 1);
    const u16* Kc = Kl[cur];
    const u16* Vc = Vl[cur];

    // QK^T swapped, both q-groups per K-frag read: S[k rows][q cols]
    f32x4 sv[2][4];
    __builtin_amdgcn_s_setprio(1);
#pragma unroll
    for (int fk = 0; fk < 4; ++fk) {
      const int kr = fk * 16 + q;
      short8 a0 = *(const short8_a*)&Kc[kr * 64 + ((g4 ^ sw7) * 8)];
      short8 a1 = *(const short8_a*)&Kc[kr * 64 + (((g4 + 4) ^ sw7) * 8)];
#pragma unroll
      for (int u = 0; u < 2; ++u) {
        f32x4 z = (f32x4){0.f, 0.f, 0.f, 0.f};
        z = mfma16(a0, qf[u][0], z);
        z = mfma16(a1, qf[u][1], z);
        sv[u][fk] = z;
      }
    }
    __builtin_amdgcn_s_setprio(0);

    // per q-group: exp+pack -> P (same buffer, in-order wave-private LDS), PV
#pragma unroll
    for (int u = 0; u < 2; ++u) {
#pragma unroll
      for (int fk = 0; fk < 4; ++fk) {
        float p0 = fexp2(sv[u][fk][0]);
        float p1 = fexp2(sv[u][fk][1]);
        float p2 = fexp2(sv[u][fk][2]);
        float p3 = fexp2(sv[u][fk][3]);
        lp[u] += (p0 + p1) + (p2 + p3);
        uint2 pk;
        pk.x = cvtpk(p0, p1);
        pk.y = cvtpk(p2, p3);
        *(uint2_a*)&Pw[poff[fk]] = pk;
      }
      short8 pa0 = *(const short8_a*)&Pw[q * 64 + ((g4 ^ sw7) * 8)];
      short8 pa1 = *(const short8_a*)&Pw[q * 64 + (((g4 + 4) ^ sw7) * 8)];
      __builtin_amdgcn_s_setprio(1);
#pragma unroll
      for (int fd = 0; fd < 4; ++fd) {
        const int vrow = fd * 16 + q;
        short8 vb0 = *(const short8_a*)&Vc[vrow * 64 + ((g4 ^ sw7) * 8)];
        short8 vb1 = *(const short8_a*)&Vc[vrow * 64 + (((g4 + 4) ^ sw7) * 8)];
        cacc[u][fd] = mfma16(pa0, vb0, cacc[u][fd]);
        cacc[u][fd] = mfma16(pa1, vb1, cacc[u][fd]);
      }
      __builtin_amdgcn_s_setprio(0);
    }
  }

  // epilogue per q-group: l reduction + ctx write ([B,S,E] for O projection)
#pragma unroll
  for (int u = 0; u < 2; ++u) {
    float l = lp[u];
    l += __shfl_xor(l, 16);
    l += __shfl_xor(l, 32);
    const int q0 = qt * 128 + w * 32 + u * 16 + (lane >> 4) * 4;
#pragma unroll
    for (int r = 0; r < 4; ++r) {
      float inv = 1.f / __shfl(l, (lane >> 4) * 4 + r);
#pragma unroll
      for (int fd = 0; fd < 4; ++fd) {
        int d = fd * 16 + q;
        ctx[((size_t)b * SEQ + q0 + r) * ED + h * HD + d] = f2bf(cacc[u][fd][r] * inv);
      }
    }
  }
}

extern "C" void kernel_launch(void* const* d_in, const int* in_sizes, int n_in,
                              void* d_out, int out_size, void* d_ws, size_t ws_size,
                              hipStream_t stream) {
  (void)in_sizes; (void)n_in; (void)out_size; (void)ws_size;
  const float* x  = (const float*)d_in[0];
  const float* Wq = (const float*)d_in[1];
  const float* bq = (const float*)d_in[2];
  const float* Wk = (const float*)d_in[3];
  const float* bk = (const float*)d_in[4];
  const float* Wv = (const float*)d_in[5];
  const float* bv = (const float*)d_in[6];
  const float* Wo = (const float*)d_in[7];
  const float* bo = (const float*)d_in[8];

  char* ws = (char*)d_ws;
  u16* x16 = (u16*)(ws);                       // 16 MB (reused as ctx16)
  u16* Wqt = (u16*)(ws + (16ull << 20));       // 2 MB
  u16* Wkt = (u16*)(ws + (18ull << 20));       // 2 MB
  u16* Wvt = (u16*)(ws + (20ull << 20));       // 2 MB
  u16* Wot = (u16*)(ws + (22ull << 20));       // 2 MB
  u16* Q16 = (u16*)(ws + (24ull << 20));       // 16 MB
  u16* K16 = (u16*)(ws + (40ull << 20));       // 4 MB
  u16* VT16 = (u16*)(ws + (44ull << 20));      // 4 MB  -> total 48 MB
  u16* ctx16 = x16;

  prep_kernel<<<9216, 256, 0, stream>>>(x, x16, Wq, Wk, Wv, Wo, Wqt, Wkt, Wvt, Wot);

  qkv_gemm<<<dim3(8, 96), 256, 0, stream>>>(x16, Wqt, Wkt, Wvt, bq, bk, bv,
                                            Q16, K16, VT16);

  attn_kernel<<<1024, 256, 0, stream>>>(Q16, K16, VT16, ctx16);

  out_gemm<<<dim3(8, 64), 256, 0, stream>>>(ctx16, Wot, bo, (float*)d_out);
}